// Round 9
// baseline (179.285 us; speedup 1.0000x reference)
//
#include <hip/hip_runtime.h>
#include <hip/hip_bf16.h>

typedef __bf16 bf16_t;
typedef __bf16 bf16x4 __attribute__((ext_vector_type(4)));
typedef __bf16 bf16x8 __attribute__((ext_vector_type(8)));
typedef float floatx4 __attribute__((ext_vector_type(4)));

#define N_NODES 4096
#define F_IN 128
#define NUM_HEADS 4
#define D_HID 64
#define F_OUT 256  // NUM_HEADS * D_HID
#define NEG_SLOPE 0.2f

// ---------------------------------------------------------------------------
// Kernel 1: projections (f32 in; GB bf16 fragment-linear; el/E1r/E2r f32).
//   GB: g[j][h*64+f] stored so a 16x16x32 MFMA B-fragment is contiguous 1 KB:
//   GB[h][j>>5][f>>4][lane=(f&15)+16*((j>>3)&3)][j&7].
//   el[h][j]  = <ga[j,h,:], w_attn[:32]>
//   E1r[h][j] = exp(<ga[j,h,:], w_attn[32:]>),  E2r[h][j] = exp(0.2*<...>)
// 1024 blocks x 384 threads; block handles 4 nodes.
// ---------------------------------------------------------------------------
__global__ __launch_bounds__(384) void proj_kernel(
    const float* __restrict__ hmat, const float* __restrict__ Wp,
    const float* __restrict__ Wa, const float* __restrict__ wattn,
    bf16_t* __restrict__ GB, float* __restrict__ el,
    float* __restrict__ E1r, float* __restrict__ E2r)
{
    __shared__ float hl[4][F_IN];
    const int t = threadIdx.x;
    const int j0 = blockIdx.x * 4;

    if (t < 128) {
        const int jl = t >> 5, m0 = (t & 31) * 4;
        *reinterpret_cast<float4*>(&hl[jl][m0]) =
            *reinterpret_cast<const float4*>(&hmat[(size_t)(j0 + jl) * F_IN + m0]);
    }
    __syncthreads();

    float acc[4] = {0.f, 0.f, 0.f, 0.f};

    const float* wptr;
    int stride;
    if (t < 256) { wptr = Wp + t;         stride = 256; }
    else         { wptr = Wa + (t - 256); stride = 128; }

    for (int m = 0; m < F_IN; m += 4) {
        const float w0 = wptr[(size_t)(m + 0) * stride];
        const float w1 = wptr[(size_t)(m + 1) * stride];
        const float w2 = wptr[(size_t)(m + 2) * stride];
        const float w3 = wptr[(size_t)(m + 3) * stride];
#pragma unroll
        for (int jl = 0; jl < 4; ++jl) {
            const float4 hv = *reinterpret_cast<const float4*>(&hl[jl][m]);
            acc[jl] = fmaf(hv.w, w3, fmaf(hv.z, w2, fmaf(hv.y, w1, fmaf(hv.x, w0, acc[jl]))));
        }
    }

    if (t < 256) {
        const int h = t >> 6, f = t & 63;
        bf16x4 o;
#pragma unroll
        for (int q = 0; q < 4; ++q) o[q] = (bf16_t)acc[q];
        const size_t base = ((((size_t)h * 128 + (j0 >> 5)) * 4 + (f >> 4)) * 64
                             + (f & 15) + 16 * ((j0 >> 3) & 3)) * 8 + (j0 & 7);
        *reinterpret_cast<bf16x4*>(&GB[base]) = o;
    } else {
        const int ta = t - 256;          // waves 4,5; 32-lane group per head
        const int ha = ta >> 5, k = ta & 31;
        const float wl = wattn[k], wr = wattn[32 + k];
#pragma unroll
        for (int jl = 0; jl < 4; ++jl) {
            float vl = acc[jl] * wl;
            float vr = acc[jl] * wr;
#pragma unroll
            for (int s = 16; s >= 1; s >>= 1) {
                vl += __shfl_xor(vl, s, 64);
                vr += __shfl_xor(vr, s, 64);
            }
            if (k == 0) {
                el[ha * N_NODES + j0 + jl]  = vl;
                E1r[ha * N_NODES + j0 + jl] = __expf(vr);
                E2r[ha * N_NODES + j0 + jl] = __expf(NEG_SLOPE * vr);
            }
        }
    }
}

// ---------------------------------------------------------------------------
// Kernel 2: fully barrier-free, LDS-free fused attention.
// Grid (256 i-tiles of 16 rows, njc) x 256 threads = 4 waves (wave = head).
// Lane l builds its A-fragment entirely in registers:
//   P(i0+(l&15), jT+quad*8+q) from DIRECT adj loads (2xfloat4/lane; the 4
//   head-waves of a block read the SAME 16 adj rows -> L1 reuse) and
//   coalesced E1r/E2r tables; B-frags are contiguous 1 KB loads from
//   fragment-linear GB (L2-resident). Den via all-ones-B MFMA.
// No __syncthreads anywhere -> no vmcnt(0) drains; the scoreboard plus
// 16 waves/CU overlap iterations (fine-grained vmcnt, hipBLASLt-style).
// __launch_bounds__(256,4): 128-VGPR cap, 4 blocks/CU.
// ---------------------------------------------------------------------------
__global__ __launch_bounds__(256, 4) void attn_kernel(
    const float* __restrict__ adj, const bf16_t* __restrict__ GB,
    const float* __restrict__ el, const float* __restrict__ E1r,
    const float* __restrict__ E2r,
    float* __restrict__ numout, float* __restrict__ den_g,
    int njc, int ntiles)
{
    const int tid = threadIdx.x;
    const int i0  = blockIdx.x * 16;
    const int jc  = blockIdx.y;
    const int jT0 = jc * ntiles * 64;

    const int hh   = tid >> 6;            // wave = head
    const int lane = tid & 63;
    const int m    = lane & 15;           // A row / D col
    const int quad = lane >> 4;

    // i-side exponential factors (this wave's head only)
    const float eli = el[hh * N_NODES + i0 + m];
    const float E1i = __expf(eli);
    const float E2i = __expf(NEG_SLOPE * eli);
    const float Ti  = __expf(-eli);

    // per-lane A-side pointers
    const float* adjl = adj + (size_t)(i0 + m) * N_NODES + quad * 8;
    const float* E1p  = E1r + hh * N_NODES + quad * 8;
    const float* E2p  = E2r + hh * N_NODES + quad * 8;
    const bf16_t* gb0 = GB + (size_t)hh * 128 * 2048 + lane * 8;

    floatx4 acc0 = {0.f, 0.f, 0.f, 0.f};
    floatx4 acc1 = acc0, acc2 = acc0, acc3 = acc0, accd = acc0;
    bf16x8 ones;
#pragma unroll
    for (int q = 0; q < 8; ++q) ones[q] = (bf16_t)1.0f;

#pragma unroll 2
    for (int k = 0; k < ntiles; ++k) {
        const int jT = jT0 + k * 64;
        const bf16_t* gbb = gb0 + (size_t)(jT >> 5) * 2048;

#pragma unroll
        for (int kt = 0; kt < 2; ++kt) {
            const int jk = jT + kt * 32;
            const float4 aa  = *reinterpret_cast<const float4*>(adjl + jk);
            const float4 ab  = *reinterpret_cast<const float4*>(adjl + jk + 4);
            const float4 e1a = *reinterpret_cast<const float4*>(E1p + jk);
            const float4 e1b = *reinterpret_cast<const float4*>(E1p + jk + 4);
            const float4 e2a = *reinterpret_cast<const float4*>(E2p + jk);
            const float4 e2b = *reinterpret_cast<const float4*>(E2p + jk + 4);

            bf16x8 af;
            af[0] = (aa.x >= 0.5f) ? (bf16_t)((e1a.x > Ti) ? E1i * e1a.x : E2i * e2a.x) : (bf16_t)0.f;
            af[1] = (aa.y >= 0.5f) ? (bf16_t)((e1a.y > Ti) ? E1i * e1a.y : E2i * e2a.y) : (bf16_t)0.f;
            af[2] = (aa.z >= 0.5f) ? (bf16_t)((e1a.z > Ti) ? E1i * e1a.z : E2i * e2a.z) : (bf16_t)0.f;
            af[3] = (aa.w >= 0.5f) ? (bf16_t)((e1a.w > Ti) ? E1i * e1a.w : E2i * e2a.w) : (bf16_t)0.f;
            af[4] = (ab.x >= 0.5f) ? (bf16_t)((e1b.x > Ti) ? E1i * e1b.x : E2i * e2b.x) : (bf16_t)0.f;
            af[5] = (ab.y >= 0.5f) ? (bf16_t)((e1b.y > Ti) ? E1i * e1b.y : E2i * e2b.y) : (bf16_t)0.f;
            af[6] = (ab.z >= 0.5f) ? (bf16_t)((e1b.z > Ti) ? E1i * e1b.z : E2i * e2b.z) : (bf16_t)0.f;
            af[7] = (ab.w >= 0.5f) ? (bf16_t)((e1b.w > Ti) ? E1i * e1b.w : E2i * e2b.w) : (bf16_t)0.f;

            const bf16x8 b0 = *reinterpret_cast<const bf16x8*>(gbb + kt * 2048);
            const bf16x8 b1 = *reinterpret_cast<const bf16x8*>(gbb + kt * 2048 + 512);
            const bf16x8 b2 = *reinterpret_cast<const bf16x8*>(gbb + kt * 2048 + 1024);
            const bf16x8 b3 = *reinterpret_cast<const bf16x8*>(gbb + kt * 2048 + 1536);

            accd = __builtin_amdgcn_mfma_f32_16x16x32_bf16(af, ones, accd, 0, 0, 0);
            acc0 = __builtin_amdgcn_mfma_f32_16x16x32_bf16(af, b0, acc0, 0, 0, 0);
            acc1 = __builtin_amdgcn_mfma_f32_16x16x32_bf16(af, b1, acc1, 0, 0, 0);
            acc2 = __builtin_amdgcn_mfma_f32_16x16x32_bf16(af, b2, acc2, 0, 0, 0);
            acc3 = __builtin_amdgcn_mfma_f32_16x16x32_bf16(af, b3, acc3, 0, 0, 0);
        }
    }

    // epilogue: C/D row = quad*4 + r, col = m; den replicated in accd[r]
    const int ibase = i0 + quad * 4;
    if (njc == 1) {
#pragma unroll
        for (int rr = 0; rr < 4; ++rr) {
            const float rd = 1.0f / accd[rr];
            float* dst = numout + (size_t)(ibase + rr) * F_OUT + hh * D_HID + m;
            dst[0]  = acc0[rr] * rd;
            dst[16] = acc1[rr] * rd;
            dst[32] = acc2[rr] * rd;
            dst[48] = acc3[rr] * rd;
        }
    } else {
        float* nrow = numout + (size_t)jc * ((size_t)N_NODES * F_OUT);
#pragma unroll
        for (int rr = 0; rr < 4; ++rr) {
            float* dst = nrow + (size_t)(ibase + rr) * F_OUT + hh * D_HID + m;
            dst[0]  = acc0[rr];
            dst[16] = acc1[rr];
            dst[32] = acc2[rr];
            dst[48] = acc3[rr];
        }
        if (m == 0) {
#pragma unroll
            for (int rr = 0; rr < 4; ++rr)
                den_g[((size_t)jc * N_NODES + ibase + rr) * NUM_HEADS + hh] = accd[rr];
        }
    }
}

// ---------------------------------------------------------------------------
// Kernel 3 (njc>1): sum chunk partials, divide, store f32.
// ---------------------------------------------------------------------------
__global__ __launch_bounds__(256) void reduce_kernel(
    const float* __restrict__ num, const float* __restrict__ den,
    float* __restrict__ out, int njc)
{
    const int idx = blockIdx.x * 256 + threadIdx.x;
    const int i  = idx >> 8;
    const int c  = idx & 255;
    const int hh = c >> 6;
    float n = 0.f, d = 0.f;
    for (int jc = 0; jc < njc; ++jc) {
        n += num[(size_t)jc * ((size_t)N_NODES * F_OUT) + idx];
        d += den[((size_t)jc * N_NODES + i) * NUM_HEADS + hh];
    }
    out[idx] = n / d;
}

// ---------------------------------------------------------------------------
extern "C" void kernel_launch(void* const* d_in, const int* in_sizes, int n_in,
                              void* d_out, int out_size, void* d_ws, size_t ws_size,
                              hipStream_t stream)
{
    const float* hmat = (const float*)d_in[0];   // (4096, 128) f32
    const float* adj  = (const float*)d_in[1];   // (4096, 4096) f32
    const float* Wp   = (const float*)d_in[2];   // (128, 256) f32
    const float* Wa   = (const float*)d_in[3];   // (128, 128) f32
    const float* watt = (const float*)d_in[4];   // (64,) f32
    float* out = (float*)d_out;                  // (4096, 256) f32

    char* ws = (char*)d_ws;
    bf16_t* GB  = (bf16_t*)ws;                                   // 2 MiB
    float*  el  = (float*)(ws + (2ull << 20));                   // 64 KiB
    float*  E1r = (float*)(ws + (2ull << 20) + (64ull << 10));   // 64 KiB
    float*  E2r = (float*)(ws + (2ull << 20) + (128ull << 10));  // 64 KiB
    const size_t baseoff = (2ull << 20) + (192ull << 10);

    const size_t num_bytes = (size_t)N_NODES * F_OUT * 4;        // 4 MiB per chunk
    const size_t den_bytes = (size_t)N_NODES * NUM_HEADS * 4;    // 64 KiB per chunk
    const int njc = (ws_size >= baseoff + 4 * (num_bytes + den_bytes)) ? 4 : 2;

    float* num = (float*)(ws + baseoff);
    float* den = (float*)(ws + baseoff + (size_t)njc * num_bytes);

    proj_kernel<<<1024, 384, 0, stream>>>(hmat, Wp, Wa, watt, GB, el, E1r, E2r);
    attn_kernel<<<dim3(256, njc), 256, 0, stream>>>(adj, GB, el, E1r, E2r,
                                                    num, den, njc, (N_NODES / njc) / 64);
    reduce_kernel<<<(N_NODES * F_OUT) / 256, 256, 0, stream>>>(num, den, out, njc);
}